// Round 10
// baseline (298.290 us; speedup 1.0000x reference)
//
#include <hip/hip_runtime.h>

// Attention layer, MI355X. Internal bf16 MFMA compute (tolerance 7e-2 permits).
// R10 pipeline: cvt5 (one launch) -> fused QKV GEMM w/ RoPE+V^T epilogue -> flash
// (R5) -> out GEMM. rope_kernel / vtrans_kernel deleted (fused); QKV BN=128 ->
// LDS ring 48KB -> 3 blocks/CU.
// gemmT core (R9, proven): BM=128 BN=128 BK=32, ring-3, 1 barrier/tile, counted
// per-wave vmcnt(2), T2 both-sides swizzle, XCD swizzle, exact rounds.
// Epilogue fusion: RoPE via __shfl_xor(v,1) pair + cos/sin tables (Q scaled by
// log2e/sqrt(HD)); V written directly transposed [bh][hd][s] as b64.

#define SQ 2048
#define DQ 2048
#define HQ 16
#define HDQ 128

typedef short bf16x8 __attribute__((ext_vector_type(8)));
typedef short bf16x4 __attribute__((ext_vector_type(4)));
typedef float f32x4 __attribute__((ext_vector_type(4)));

#define WAITVM4 asm volatile("s_waitcnt vmcnt(4)" ::: "memory")
#define WAITVM2 asm volatile("s_waitcnt vmcnt(2)" ::: "memory")
#define WAITVM0 asm volatile("s_waitcnt vmcnt(0)" ::: "memory")

__device__ __forceinline__ short f2bf(float f) {
  union { float f; unsigned u; } v; v.f = f;
  unsigned r = (v.u + 0x7FFFu + ((v.u >> 16) & 1u)) >> 16;
  return (short)r;
}
__device__ __forceinline__ float bf2f(short b) {
  union { unsigned u; float f; } v; v.u = ((unsigned)(unsigned short)b) << 16;
  return v.f;
}
__device__ __forceinline__ void gload_lds16(const void* g, void* l) {
  __builtin_amdgcn_global_load_lds(
      (const __attribute__((address_space(1))) void*)g,
      (__attribute__((address_space(3))) void*)l, 16, 0, 0);
}

// ---------- fp32 -> bf16, all 5 inputs in one launch ----------
// blocks 0..4095: x (1048576 vecs); 4096+w*2048..: weight w (524288 vecs each).
__global__ void cvt5_kernel(const float* __restrict__ x, const float* __restrict__ wq,
                            const float* __restrict__ wk, const float* __restrict__ wv,
                            const float* __restrict__ wo, short* __restrict__ xb,
                            short* __restrict__ wqb, short* __restrict__ wkb,
                            short* __restrict__ wvb, short* __restrict__ wob) {
  int bi = blockIdx.x;
  const float* src;
  short* dst;
  int off;
  if (bi < 4096) {
    src = x; dst = xb; off = bi;
  } else {
    int t = bi - 4096, wsel = t >> 11;
    off = t & 2047;
    src = (wsel == 0) ? wq : (wsel == 1) ? wk : (wsel == 2) ? wv : wo;
    dst = (wsel == 0) ? wqb : (wsel == 1) ? wkb : (wsel == 2) ? wvb : wob;
  }
  int i = off * 256 + threadIdx.x;
  const f32x4* p = (const f32x4*)src + (size_t)i * 2;
  f32x4 a = p[0], b = p[1];
  bf16x8 o;
  o[0] = f2bf(a[0]); o[1] = f2bf(a[1]); o[2] = f2bf(a[2]); o[3] = f2bf(a[3]);
  o[4] = f2bf(b[0]); o[5] = f2bf(b[1]); o[6] = f2bf(b[2]); o[7] = f2bf(b[3]);
  *((bf16x8*)dst + i) = o;
}

// ---------- gemmT: BM=128 x BN=128 x BK=32, ring-3, 8 waves (2M x 4N), 1 barrier/tile ----------
// MODE 0: A[4096][2048] x W[6144][2048] fused QKV. Epilogue: RoPE(Q,K) fused via
// lane-pair shuffle + cos/sin tables (Q scaled log2e/sqrt(HD)); V written directly
// transposed to oV[bh][hd][s] (b64). MODE 1: -> fp32 [M][2048].
template <int BN, int MODE>
__global__ __launch_bounds__(512, 4) void gemmT(const short* __restrict__ A,
                                                const short* __restrict__ W,
                                                short* __restrict__ oQ, short* __restrict__ oK,
                                                short* __restrict__ oV, float* __restrict__ oF,
                                                const float* __restrict__ cosT,
                                                const float* __restrict__ sinT) {
  constexpr int NFR = BN / 64;   // B frags per wave
  constexpr int NIB = BN / 16;   // B stage issues (64 granules each)
  constexpr int NBX = (MODE == 0) ? (6144 / BN) : (2048 / BN);
  __shared__ __align__(16) short As[3][128 * 32];
  __shared__ __align__(16) short Bs[3][BN * 32];
  const int K = DQ;
  const int NT = K / 32;  // 64
  int nwg = gridDim.x, cpx = nwg >> 3;
  int swz = (blockIdx.x & 7) * cpx + (blockIdx.x >> 3);
  int bx = swz % NBX, by = swz / NBX;
  int m0 = by * 128, n0 = bx * BN;
  int tid = threadIdx.x, wid = tid >> 6, lane = tid & 63;
  int wr = wid >> 2, wc = wid & 3;
  f32x4 acc[4][NFR] = {};

  auto stageA = [&](int kt, int buf) {
    int g = wid * 64 + lane;
    int r = g >> 2, q = g & 3;
    gload_lds16(A + (size_t)(m0 + r) * K + kt * 32 + ((q ^ (((r >> 3) & 1) << 1)) * 8),
                &As[buf][wid * 512]);
  };
  auto stageB = [&](int kt, int buf) {
#pragma unroll
    for (int i = wid; i < NIB; i += 8) {
      int g = i * 64 + lane;
      int r = g >> 2, q = g & 3;
      gload_lds16(W + (size_t)(n0 + r) * K + kt * 32 + ((q ^ (((r >> 3) & 1) << 1)) * 8),
                  &Bs[buf][i * 512]);
    }
  };

  stageA(0, 0); stageB(0, 0);
  stageA(1, 1); stageB(1, 1);
  WAITVM2;
  __builtin_amdgcn_s_barrier();

  int cc = (lane >> 4) * 8;
  int cur = 0, nbuf = 2;
#pragma unroll 1
  for (int t = 0; t < NT; ++t) {
    bool st = (t + 2) < NT;
    bf16x8 bfr[NFR], af[4];
#pragma unroll
    for (int nf = 0; nf < NFR; ++nf) {
      int br = wc * (BN / 4) + nf * 16 + (lane & 15);
      bfr[nf] = *(const bf16x8*)&Bs[cur][br * 32 + (cc ^ (((br >> 3) & 1) << 4))];
    }
#pragma unroll
    for (int i = 0; i < 4; ++i) {
      int fr = wr * 64 + i * 16 + (lane & 15);
      af[i] = *(const bf16x8*)&As[cur][fr * 32 + (cc ^ (((fr >> 3) & 1) << 4))];
    }
    if (st) { stageA(t + 2, nbuf); stageB(t + 2, nbuf); }
    __builtin_amdgcn_s_setprio(1);
#pragma unroll
    for (int i = 0; i < 4; ++i)
#pragma unroll
      for (int nf = 0; nf < NFR; ++nf)
        acc[i][nf] = __builtin_amdgcn_mfma_f32_16x16x32_bf16(af[i], bfr[nf], acc[i][nf], 0, 0, 0);
    __builtin_amdgcn_s_setprio(0);
    if (st) { WAITVM2; } else { WAITVM0; }
    __builtin_amdgcn_s_barrier();
    cur = (cur == 2) ? 0 : cur + 1;
    nbuf = (nbuf == 2) ? 0 : nbuf + 1;
  }
  // ---- epilogue ----
#pragma unroll
  for (int mf = 0; mf < 4; ++mf) {
    int mb = m0 + wr * 64 + mf * 16 + (lane >> 4) * 4;
#pragma unroll
    for (int nf = 0; nf < NFR; ++nf) {
      int n_lin = n0 + wc * (BN / 4) + nf * 16 + (lane & 15);
      if (MODE == 1) {
#pragma unroll
        for (int j = 0; j < 4; ++j)
          oF[(size_t)(mb + j) * DQ + n_lin] = acc[mf][nf][j];
      } else {
        int zsel = n_lin >> 11, col = n_lin & 2047;
        int h = col >> 7, hd = col & 127, ii = hd >> 1;
        float sgn = (hd & 1) ? 1.f : -1.f;
        float scl = (zsel == 0) ? 0.12751744779976827f : 1.f;  // log2e/sqrt(HD) for Q
        float ov[4];
#pragma unroll
        for (int j = 0; j < 4; ++j) {
          int m = mb + j;
          int s = m & 2047, b = m >> 11;
          float v = acc[mf][nf][j];
          float vp = __shfl_xor(v, 1);  // RoPE pair value (hd^1), same (mf,nf,j)
          if (zsel < 2) {
            float c = cosT[s * 64 + ii], sn = sinT[s * 64 + ii];
            float o = (v * c + sgn * vp * sn) * scl;
            short* oT = zsel ? oK : oQ;
            oT[(((size_t)(b * HQ + h)) * SQ + s) * HDQ + hd] = f2bf(o);
          } else {
            ov[j] = v;
          }
        }
        if (zsel == 2) {  // V -> transposed [bh][hd][s], 4 consecutive s = one b64
          int b = mb >> 11, s = mb & 2047;
          bf16x4 pk;
          pk[0] = f2bf(ov[0]); pk[1] = f2bf(ov[1]); pk[2] = f2bf(ov[2]); pk[3] = f2bf(ov[3]);
          *(bf16x4*)&oV[(((size_t)(b * HQ + h)) * HDQ + hd) * SQ + s] = pk;
        }
      }
    }
  }
}

// ---------- Flash attention R5: KVBLK=32 dbuf, swapped QK^T, 4 blocks/CU ----------
__device__ __forceinline__ void stage_kv32(const short* kbase, const short* vbase, int k0,
                                           short* KsB, short* VtB, int w, int lane) {
#pragma unroll
  for (int i = 0; i < 2; ++i) {
    int c = i * 4 + w;
    int ch = c * 64 + lane;
    int r = ch >> 4, c8 = (ch & 15) * 8;                   // K: [32 rows][128 d]
    gload_lds16(kbase + (size_t)(k0 + r) * HDQ + (c8 ^ ((r & 7) << 3)), KsB + c * 512);
    int d = ch >> 2, k8 = (ch & 3) * 8;                    // V^T: [128 d][32 k]
    gload_lds16(vbase + (size_t)d * SQ + k0 + (k8 ^ (((d >> 1) & 3) << 3)), VtB + c * 512);
  }
}

__global__ __launch_bounds__(256, 4) void flash_kernel(const short* __restrict__ qb,
                                                       const short* __restrict__ kb,
                                                       const short* __restrict__ vtb,
                                                       short* __restrict__ ab) {
  __shared__ __align__(16) short Ks[2][32 * 128];
  __shared__ __align__(16) short Vt[2][128 * 32];
  __shared__ __align__(16) short Pl[4][16 * 32];
  int x = blockIdx.x, bh = blockIdx.y;
  int qt = (bh & 8) ? (31 - x) : x;
  int q0 = qt * 64;
  int tid = threadIdx.x, w = tid >> 6, lane = tid & 63;
  int g = lane >> 4, qcol = lane & 15;
  int qw0 = q0 + w * 16;
  const short* qbase = qb + (size_t)bh * SQ * HDQ;
  const short* kbase = kb + (size_t)bh * SQ * HDQ;
  const short* vbase = vtb + (size_t)bh * HDQ * SQ;
  int b = bh >> 4, h = bh & 15;

  bf16x8 qf[4];
#pragma unroll
  for (int ccq = 0; ccq < 4; ++ccq)
    qf[ccq] = *(const bf16x8*)&qbase[(size_t)(qw0 + qcol) * HDQ + ccq * 32 + g * 8];

  f32x4 oacc[8] = {};
  float m_st = -1e30f, l_st = 0.f;
  int nt = 2 * qt + 2;
  stage_kv32(kbase, vbase, 0, Ks[0], Vt[0], w, lane);
#pragma unroll 1
  for (int t = 0; t < nt; ++t) {
    int cur = t & 1;
    int k0 = t * 32;
    __builtin_amdgcn_s_barrier();
    if (t + 1 < nt) {
      stage_kv32(kbase, vbase, (t + 1) * 32, Ks[cur ^ 1], Vt[cur ^ 1], w, lane);
      WAITVM4;
    } else {
      WAITVM0;
    }
    __builtin_amdgcn_s_barrier();
    if (k0 > qw0 + 15) continue;
    f32x4 sacc[2] = {};
    __builtin_amdgcn_s_setprio(1);
#pragma unroll
    for (int nf = 0; nf < 2; ++nf) {
      int rk = nf * 16 + qcol;
#pragma unroll
      for (int ccq = 0; ccq < 4; ++ccq) {
        int ck = ccq * 32 + g * 8;
        bf16x8 kf = *(const bf16x8*)&Ks[cur][rk * 128 + (ck ^ ((rk & 7) << 3))];
        sacc[nf] = __builtin_amdgcn_mfma_f32_16x16x32_bf16(kf, qf[ccq], sacc[nf], 0, 0, 0);
      }
    }
    __builtin_amdgcn_s_setprio(0);
    int q = qw0 + qcol;
    if (k0 + 31 > qw0) {
#pragma unroll
      for (int nf = 0; nf < 2; ++nf)
#pragma unroll
        for (int j = 0; j < 4; ++j) {
          int k = k0 + nf * 16 + g * 4 + j;
          if (k > q) sacc[nf][j] = -1e9f;
        }
    }
    float mt = fmaxf(fmaxf(fmaxf(sacc[0][0], sacc[0][1]), fmaxf(sacc[0][2], sacc[0][3])),
                     fmaxf(fmaxf(sacc[1][0], sacc[1][1]), fmaxf(sacc[1][2], sacc[1][3])));
    mt = fmaxf(mt, __shfl_xor(mt, 16));
    mt = fmaxf(mt, __shfl_xor(mt, 32));
    float mn = fmaxf(m_st, mt);
    float al = exp2f(m_st - mn);
    float p0[4], p1[4];
    float ls = 0.f;
#pragma unroll
    for (int j = 0; j < 4; ++j) { p0[j] = exp2f(sacc[0][j] - mn); ls += p0[j]; }
#pragma unroll
    for (int j = 0; j < 4; ++j) { p1[j] = exp2f(sacc[1][j] - mn); ls += p1[j]; }
    l_st = l_st * al + ls;
    m_st = mn;
    int sw = (qcol & 3) * 8;
    {
      bf16x4 pk;
      pk[0] = f2bf(p0[0]); pk[1] = f2bf(p0[1]); pk[2] = f2bf(p0[2]); pk[3] = f2bf(p0[3]);
      *(bf16x4*)&Pl[w][qcol * 32 + ((g * 4) ^ sw)] = pk;
      pk[0] = f2bf(p1[0]); pk[1] = f2bf(p1[1]); pk[2] = f2bf(p1[2]); pk[3] = f2bf(p1[3]);
      *(bf16x4*)&Pl[w][qcol * 32 + ((16 + g * 4) ^ sw)] = pk;
    }
    f32x4 alv;
    alv[0] = __shfl(al, g * 4 + 0);
    alv[1] = __shfl(al, g * 4 + 1);
    alv[2] = __shfl(al, g * 4 + 2);
    alv[3] = __shfl(al, g * 4 + 3);
#pragma unroll
    for (int df = 0; df < 8; ++df) oacc[df] *= alv;
    bf16x8 pf = *(const bf16x8*)&Pl[w][qcol * 32 + ((g * 8) ^ sw)];
    __builtin_amdgcn_s_setprio(1);
#pragma unroll
    for (int df = 0; df < 8; ++df) {
      int rd = df * 16 + qcol;
      bf16x8 vf = *(const bf16x8*)&Vt[cur][rd * 32 + ((g * 8) ^ (((rd >> 1) & 3) << 3))];
      oacc[df] = __builtin_amdgcn_mfma_f32_16x16x32_bf16(pf, vf, oacc[df], 0, 0, 0);
    }
    __builtin_amdgcn_s_setprio(0);
  }
  l_st += __shfl_xor(l_st, 16);
  l_st += __shfl_xor(l_st, 32);
  float inv = 1.0f / l_st;
  f32x4 invv;
  invv[0] = __shfl(inv, g * 4 + 0);
  invv[1] = __shfl(inv, g * 4 + 1);
  invv[2] = __shfl(inv, g * 4 + 2);
  invv[3] = __shfl(inv, g * 4 + 3);
#pragma unroll
  for (int df = 0; df < 8; ++df)
#pragma unroll
    for (int j = 0; j < 4; ++j) {
      int qq = qw0 + g * 4 + j;
      int dd = df * 16 + qcol;
      ab[((size_t)b * SQ + qq) * DQ + h * HDQ + dd] = f2bf(oacc[df][j] * invv[j]);
    }
}

extern "C" void kernel_launch(void* const* d_in, const int* in_sizes, int n_in,
                              void* d_out, int out_size, void* d_ws, size_t ws_size,
                              hipStream_t stream) {
  (void)in_sizes; (void)n_in; (void)out_size; (void)ws_size;
  const float* x  = (const float*)d_in[0];
  const float* wq = (const float*)d_in[1];
  const float* wk = (const float*)d_in[2];
  const float* wv = (const float*)d_in[3];
  const float* wo = (const float*)d_in[4];
  const float* fc = (const float*)d_in[5];
  const float* fs = (const float*)d_in[6];
  // d_in[7] = mask (implemented analytically: causal, start_pos=0), d_in[8] = start_pos
  float* out = (float*)d_out;

  short* xb  = (short*)d_ws;              // 8,388,608 elems
  short* wqb = xb + (size_t)8388608;      // wq,wk,wv contiguous: 6144 rows x 2048
  short* wkb = wqb + (size_t)4194304;
  short* wvb = wkb + (size_t)4194304;
  short* wob = wvb + (size_t)4194304;
  short* qb  = wob + (size_t)4194304;     // [B,H,S,HD] bf16 (RoPE'd + scaled in epilogue)
  short* kb  = qb + (size_t)8388608;      // [B,H,S,HD] bf16 (RoPE'd)
  short* ab  = kb + (size_t)8388608;      // attn out [B,S,D] bf16
  // V^T [BH,HD,S] overlaid into d_out second half (dead before final GEMM writes it)
  short* vtb = (short*)d_out + (size_t)8388608;

  cvt5_kernel<<<12288, 256, 0, stream>>>(x, wq, wk, wv, wo, xb, wqb, wkb, wvb, wob);

  // fused QKV: M=4096, N=6144; 48x32 tiles of 128x128 -> 1536 blocks = 2 exact rounds
  // epilogue fuses RoPE (Q scaled by log2e/sqrt(HD)) and V^T write
  gemmT<128, 0><<<dim3(1536), 512, 0, stream>>>(xb, wqb, qb, kb, vtb, nullptr, fc, fs);

  flash_kernel<<<dim3(32, 32), 256, 0, stream>>>(qb, kb, vtb, ab);

  // out-proj: M=4096, N=2048; 16x32 tiles of 128x128 -> 512 blocks = 1 exact round
  gemmT<128, 1><<<dim3(512), 512, 0, stream>>>(ab, wob, nullptr, nullptr, nullptr, out,
                                               nullptr, nullptr);
}

// Round 11
// 277.483 us; speedup vs baseline: 1.0750x; 1.0750x over previous
//
#include <hip/hip_runtime.h>

// Attention layer, MI355X. Internal bf16 MFMA compute (tolerance 7e-2 permits).
// R11: cvt5 -> fused QKV GEMM (BN=192 + RoPE/V^T epilogue) -> flash (R5) -> out GEMM.
// gemmT: BM=128 BK=32 ring-3, 1 barrier/tile, counted per-wave vmcnt, T2 swizzle.
// NEW: 2D XCD supertiling — each XCD owns a (by x bx) chunk ordered so its ~64
// co-resident blocks form an 8x8 supertile (L2 working set 25MB -> 10MB).
// QKV: BN=192, 1024 blocks = 2 exact rounds. Out: BN=128, 512 blocks = 1 round.

#define SQ 2048
#define DQ 2048
#define HQ 16
#define HDQ 128

typedef short bf16x8 __attribute__((ext_vector_type(8)));
typedef short bf16x4 __attribute__((ext_vector_type(4)));
typedef float f32x4 __attribute__((ext_vector_type(4)));

#define WAITVM4 asm volatile("s_waitcnt vmcnt(4)" ::: "memory")
#define WAITVM3 asm volatile("s_waitcnt vmcnt(3)" ::: "memory")
#define WAITVM2 asm volatile("s_waitcnt vmcnt(2)" ::: "memory")
#define WAITVM0 asm volatile("s_waitcnt vmcnt(0)" ::: "memory")

__device__ __forceinline__ short f2bf(float f) {
  union { float f; unsigned u; } v; v.f = f;
  unsigned r = (v.u + 0x7FFFu + ((v.u >> 16) & 1u)) >> 16;
  return (short)r;
}
__device__ __forceinline__ float bf2f(short b) {
  union { unsigned u; float f; } v; v.u = ((unsigned)(unsigned short)b) << 16;
  return v.f;
}
__device__ __forceinline__ void gload_lds16(const void* g, void* l) {
  __builtin_amdgcn_global_load_lds(
      (const __attribute__((address_space(1))) void*)g,
      (__attribute__((address_space(3))) void*)l, 16, 0, 0);
}

// ---------- fp32 -> bf16, all 5 inputs in one launch ----------
__global__ void cvt5_kernel(const float* __restrict__ x, const float* __restrict__ wq,
                            const float* __restrict__ wk, const float* __restrict__ wv,
                            const float* __restrict__ wo, short* __restrict__ xb,
                            short* __restrict__ wqb, short* __restrict__ wkb,
                            short* __restrict__ wvb, short* __restrict__ wob) {
  int bi = blockIdx.x;
  const float* src;
  short* dst;
  int off;
  if (bi < 4096) {
    src = x; dst = xb; off = bi;
  } else {
    int t = bi - 4096, wsel = t >> 11;
    off = t & 2047;
    src = (wsel == 0) ? wq : (wsel == 1) ? wk : (wsel == 2) ? wv : wo;
    dst = (wsel == 0) ? wqb : (wsel == 1) ? wkb : (wsel == 2) ? wvb : wob;
  }
  int i = off * 256 + threadIdx.x;
  const f32x4* p = (const f32x4*)src + (size_t)i * 2;
  f32x4 a = p[0], b = p[1];
  bf16x8 o;
  o[0] = f2bf(a[0]); o[1] = f2bf(a[1]); o[2] = f2bf(a[2]); o[3] = f2bf(a[3]);
  o[4] = f2bf(b[0]); o[5] = f2bf(b[1]); o[6] = f2bf(b[2]); o[7] = f2bf(b[3]);
  *((bf16x8*)dst + i) = o;
}

// ---------- gemmT: BM=128 x BN x BK=32, ring-3, 8 waves (2M x 4N), 1 barrier/tile ----------
// MODE 0 (BN=192): fused QKV + RoPE/V^T epilogue. MODE 1 (BN=128): fp32 [M][2048].
template <int BN, int MODE>
__global__ __launch_bounds__(512, 4) void gemmT(const short* __restrict__ A,
                                                const short* __restrict__ W,
                                                short* __restrict__ oQ, short* __restrict__ oK,
                                                short* __restrict__ oV, float* __restrict__ oF,
                                                const float* __restrict__ cosT,
                                                const float* __restrict__ sinT) {
  constexpr int NFR = BN / 64;   // B frags per wave
  constexpr int NIB = BN / 16;   // B stage issues (64 granules each)
  __shared__ __align__(16) short As[3][128 * 32];
  __shared__ __align__(16) short Bs[3][BN * 32];
  const int K = DQ;
  const int NT = K / 32;  // 64
  // 2D XCD supertiling: resident ~64 blocks per XCD form an 8x8 supertile.
  int x = blockIdx.x, xcd = x & 7, l = x >> 3;
  int by, bx;
  if (MODE == 0) {  // 32 by x 32 bx, XCD grid 2x4, chunk 16x8, row-major 8-wide n
    int xr = xcd >> 2, xc = xcd & 3;
    by = xr * 16 + (l >> 3);
    bx = xc * 8 + (l & 7);
  } else {          // 32 by x 16 bx, XCD grid 4x2, chunk 8x8
    int xr = xcd >> 1, xc = xcd & 1;
    by = xr * 8 + (l >> 3);
    bx = xc * 8 + (l & 7);
  }
  int m0 = by * 128, n0 = bx * BN;
  int tid = threadIdx.x, wid = tid >> 6, lane = tid & 63;
  int wr = wid >> 2, wc = wid & 3;
  f32x4 acc[4][NFR] = {};

  auto stageA = [&](int kt, int buf) {
    int g = wid * 64 + lane;
    int r = g >> 2, q = g & 3;
    gload_lds16(A + (size_t)(m0 + r) * K + kt * 32 + ((q ^ (((r >> 3) & 1) << 1)) * 8),
                &As[buf][wid * 512]);
  };
  auto stageB = [&](int kt, int buf) {
#pragma unroll
    for (int i = wid; i < NIB; i += 8) {
      int g = i * 64 + lane;
      int r = g >> 2, q = g & 3;
      gload_lds16(W + (size_t)(n0 + r) * K + kt * 32 + ((q ^ (((r >> 3) & 1) << 1)) * 8),
                  &Bs[buf][i * 512]);
    }
  };

  stageA(0, 0); stageB(0, 0);
  stageA(1, 1); stageB(1, 1);
  if (BN == 192 && wid < 4) { WAITVM3; } else { WAITVM2; }
  __builtin_amdgcn_s_barrier();

  int cc = (lane >> 4) * 8;
  int cur = 0, nbuf = 2;
#pragma unroll 1
  for (int t = 0; t < NT; ++t) {
    bool st = (t + 2) < NT;
    bf16x8 bfr[NFR], af[4];
#pragma unroll
    for (int nf = 0; nf < NFR; ++nf) {
      int br = wc * (BN / 4) + nf * 16 + (lane & 15);
      bfr[nf] = *(const bf16x8*)&Bs[cur][br * 32 + (cc ^ (((br >> 3) & 1) << 4))];
    }
#pragma unroll
    for (int i = 0; i < 4; ++i) {
      int fr = wr * 64 + i * 16 + (lane & 15);
      af[i] = *(const bf16x8*)&As[cur][fr * 32 + (cc ^ (((fr >> 3) & 1) << 4))];
    }
    if (st) { stageA(t + 2, nbuf); stageB(t + 2, nbuf); }
    __builtin_amdgcn_s_setprio(1);
#pragma unroll
    for (int i = 0; i < 4; ++i)
#pragma unroll
      for (int nf = 0; nf < NFR; ++nf)
        acc[i][nf] = __builtin_amdgcn_mfma_f32_16x16x32_bf16(af[i], bfr[nf], acc[i][nf], 0, 0, 0);
    __builtin_amdgcn_s_setprio(0);
    if (st) {
      if (BN == 192 && wid < 4) { WAITVM3; } else { WAITVM2; }
    } else {
      WAITVM0;
    }
    __builtin_amdgcn_s_barrier();
    cur = (cur == 2) ? 0 : cur + 1;
    nbuf = (nbuf == 2) ? 0 : nbuf + 1;
  }
  // ---- epilogue ----
#pragma unroll
  for (int mf = 0; mf < 4; ++mf) {
    int mb = m0 + wr * 64 + mf * 16 + (lane >> 4) * 4;
#pragma unroll
    for (int nf = 0; nf < NFR; ++nf) {
      int n_lin = n0 + wc * (BN / 4) + nf * 16 + (lane & 15);
      if (MODE == 1) {
#pragma unroll
        for (int j = 0; j < 4; ++j)
          oF[(size_t)(mb + j) * DQ + n_lin] = acc[mf][nf][j];
      } else {
        int zsel = n_lin >> 11, col = n_lin & 2047;
        int h = col >> 7, hd = col & 127, ii = hd >> 1;
        float sgn = (hd & 1) ? 1.f : -1.f;
        float scl = (zsel == 0) ? 0.12751744779976827f : 1.f;  // log2e/sqrt(HD) for Q
        float ov[4];
#pragma unroll
        for (int j = 0; j < 4; ++j) {
          int m = mb + j;
          int s = m & 2047, b = m >> 11;
          float v = acc[mf][nf][j];
          float vp = __shfl_xor(v, 1);  // RoPE pair (hd^1), same (mf,nf,j)
          if (zsel < 2) {
            float c = cosT[s * 64 + ii], sn = sinT[s * 64 + ii];
            float o = (v * c + sgn * vp * sn) * scl;
            short* oT = zsel ? oK : oQ;
            oT[(((size_t)(b * HQ + h)) * SQ + s) * HDQ + hd] = f2bf(o);
          } else {
            ov[j] = v;
          }
        }
        if (zsel == 2) {  // V -> transposed [bh][hd][s], 4 consecutive s = one b64
          int b = mb >> 11, s = mb & 2047;
          bf16x4 pk;
          pk[0] = f2bf(ov[0]); pk[1] = f2bf(ov[1]); pk[2] = f2bf(ov[2]); pk[3] = f2bf(ov[3]);
          *(bf16x4*)&oV[(((size_t)(b * HQ + h)) * HDQ + hd) * SQ + s] = pk;
        }
      }
    }
  }
}

// ---------- Flash attention R5: KVBLK=32 dbuf, swapped QK^T, 4 blocks/CU ----------
__device__ __forceinline__ void stage_kv32(const short* kbase, const short* vbase, int k0,
                                           short* KsB, short* VtB, int w, int lane) {
#pragma unroll
  for (int i = 0; i < 2; ++i) {
    int c = i * 4 + w;
    int ch = c * 64 + lane;
    int r = ch >> 4, c8 = (ch & 15) * 8;                   // K: [32 rows][128 d]
    gload_lds16(kbase + (size_t)(k0 + r) * HDQ + (c8 ^ ((r & 7) << 3)), KsB + c * 512);
    int d = ch >> 2, k8 = (ch & 3) * 8;                    // V^T: [128 d][32 k]
    gload_lds16(vbase + (size_t)d * SQ + k0 + (k8 ^ (((d >> 1) & 3) << 3)), VtB + c * 512);
  }
}

__global__ __launch_bounds__(256, 4) void flash_kernel(const short* __restrict__ qb,
                                                       const short* __restrict__ kb,
                                                       const short* __restrict__ vtb,
                                                       short* __restrict__ ab) {
  __shared__ __align__(16) short Ks[2][32 * 128];
  __shared__ __align__(16) short Vt[2][128 * 32];
  __shared__ __align__(16) short Pl[4][16 * 32];
  int x = blockIdx.x, bh = blockIdx.y;
  int qt = (bh & 8) ? (31 - x) : x;
  int q0 = qt * 64;
  int tid = threadIdx.x, w = tid >> 6, lane = tid & 63;
  int g = lane >> 4, qcol = lane & 15;
  int qw0 = q0 + w * 16;
  const short* qbase = qb + (size_t)bh * SQ * HDQ;
  const short* kbase = kb + (size_t)bh * SQ * HDQ;
  const short* vbase = vtb + (size_t)bh * HDQ * SQ;
  int b = bh >> 4, h = bh & 15;

  bf16x8 qf[4];
#pragma unroll
  for (int ccq = 0; ccq < 4; ++ccq)
    qf[ccq] = *(const bf16x8*)&qbase[(size_t)(qw0 + qcol) * HDQ + ccq * 32 + g * 8];

  f32x4 oacc[8] = {};
  float m_st = -1e30f, l_st = 0.f;
  int nt = 2 * qt + 2;
  stage_kv32(kbase, vbase, 0, Ks[0], Vt[0], w, lane);
#pragma unroll 1
  for (int t = 0; t < nt; ++t) {
    int cur = t & 1;
    int k0 = t * 32;
    __builtin_amdgcn_s_barrier();
    if (t + 1 < nt) {
      stage_kv32(kbase, vbase, (t + 1) * 32, Ks[cur ^ 1], Vt[cur ^ 1], w, lane);
      WAITVM4;
    } else {
      WAITVM0;
    }
    __builtin_amdgcn_s_barrier();
    if (k0 > qw0 + 15) continue;
    f32x4 sacc[2] = {};
    __builtin_amdgcn_s_setprio(1);
#pragma unroll
    for (int nf = 0; nf < 2; ++nf) {
      int rk = nf * 16 + qcol;
#pragma unroll
      for (int ccq = 0; ccq < 4; ++ccq) {
        int ck = ccq * 32 + g * 8;
        bf16x8 kf = *(const bf16x8*)&Ks[cur][rk * 128 + (ck ^ ((rk & 7) << 3))];
        sacc[nf] = __builtin_amdgcn_mfma_f32_16x16x32_bf16(kf, qf[ccq], sacc[nf], 0, 0, 0);
      }
    }
    __builtin_amdgcn_s_setprio(0);
    int q = qw0 + qcol;
    if (k0 + 31 > qw0) {
#pragma unroll
      for (int nf = 0; nf < 2; ++nf)
#pragma unroll
        for (int j = 0; j < 4; ++j) {
          int k = k0 + nf * 16 + g * 4 + j;
          if (k > q) sacc[nf][j] = -1e9f;
        }
    }
    float mt = fmaxf(fmaxf(fmaxf(sacc[0][0], sacc[0][1]), fmaxf(sacc[0][2], sacc[0][3])),
                     fmaxf(fmaxf(sacc[1][0], sacc[1][1]), fmaxf(sacc[1][2], sacc[1][3])));
    mt = fmaxf(mt, __shfl_xor(mt, 16));
    mt = fmaxf(mt, __shfl_xor(mt, 32));
    float mn = fmaxf(m_st, mt);
    float al = exp2f(m_st - mn);
    float p0[4], p1[4];
    float ls = 0.f;
#pragma unroll
    for (int j = 0; j < 4; ++j) { p0[j] = exp2f(sacc[0][j] - mn); ls += p0[j]; }
#pragma unroll
    for (int j = 0; j < 4; ++j) { p1[j] = exp2f(sacc[1][j] - mn); ls += p1[j]; }
    l_st = l_st * al + ls;
    m_st = mn;
    int sw = (qcol & 3) * 8;
    {
      bf16x4 pk;
      pk[0] = f2bf(p0[0]); pk[1] = f2bf(p0[1]); pk[2] = f2bf(p0[2]); pk[3] = f2bf(p0[3]);
      *(bf16x4*)&Pl[w][qcol * 32 + ((g * 4) ^ sw)] = pk;
      pk[0] = f2bf(p1[0]); pk[1] = f2bf(p1[1]); pk[2] = f2bf(p1[2]); pk[3] = f2bf(p1[3]);
      *(bf16x4*)&Pl[w][qcol * 32 + ((16 + g * 4) ^ sw)] = pk;
    }
    f32x4 alv;
    alv[0] = __shfl(al, g * 4 + 0);
    alv[1] = __shfl(al, g * 4 + 1);
    alv[2] = __shfl(al, g * 4 + 2);
    alv[3] = __shfl(al, g * 4 + 3);
#pragma unroll
    for (int df = 0; df < 8; ++df) oacc[df] *= alv;
    bf16x8 pf = *(const bf16x8*)&Pl[w][qcol * 32 + ((g * 8) ^ sw)];
    __builtin_amdgcn_s_setprio(1);
#pragma unroll
    for (int df = 0; df < 8; ++df) {
      int rd = df * 16 + qcol;
      bf16x8 vf = *(const bf16x8*)&Vt[cur][rd * 32 + ((g * 8) ^ (((rd >> 1) & 3) << 3))];
      oacc[df] = __builtin_amdgcn_mfma_f32_16x16x32_bf16(pf, vf, oacc[df], 0, 0, 0);
    }
    __builtin_amdgcn_s_setprio(0);
  }
  l_st += __shfl_xor(l_st, 16);
  l_st += __shfl_xor(l_st, 32);
  float inv = 1.0f / l_st;
  f32x4 invv;
  invv[0] = __shfl(inv, g * 4 + 0);
  invv[1] = __shfl(inv, g * 4 + 1);
  invv[2] = __shfl(inv, g * 4 + 2);
  invv[3] = __shfl(inv, g * 4 + 3);
#pragma unroll
  for (int df = 0; df < 8; ++df)
#pragma unroll
    for (int j = 0; j < 4; ++j) {
      int qq = qw0 + g * 4 + j;
      int dd = df * 16 + qcol;
      ab[((size_t)b * SQ + qq) * DQ + h * HDQ + dd] = f2bf(oacc[df][j] * invv[j]);
    }
}

extern "C" void kernel_launch(void* const* d_in, const int* in_sizes, int n_in,
                              void* d_out, int out_size, void* d_ws, size_t ws_size,
                              hipStream_t stream) {
  (void)in_sizes; (void)n_in; (void)out_size; (void)ws_size;
  const float* x  = (const float*)d_in[0];
  const float* wq = (const float*)d_in[1];
  const float* wk = (const float*)d_in[2];
  const float* wv = (const float*)d_in[3];
  const float* wo = (const float*)d_in[4];
  const float* fc = (const float*)d_in[5];
  const float* fs = (const float*)d_in[6];
  // d_in[7] = mask (implemented analytically: causal, start_pos=0), d_in[8] = start_pos
  float* out = (float*)d_out;

  short* xb  = (short*)d_ws;              // 8,388,608 elems
  short* wqb = xb + (size_t)8388608;      // wq,wk,wv contiguous: 6144 rows x 2048
  short* wkb = wqb + (size_t)4194304;
  short* wvb = wkb + (size_t)4194304;
  short* wob = wvb + (size_t)4194304;
  short* qb  = wob + (size_t)4194304;     // [B,H,S,HD] bf16 (RoPE'd + scaled)
  short* kb  = qb + (size_t)8388608;      // [B,H,S,HD] bf16 (RoPE'd)
  short* ab  = kb + (size_t)8388608;      // attn out [B,S,D] bf16
  // V^T [BH,HD,S] overlaid into d_out second half (dead before final GEMM writes it)
  short* vtb = (short*)d_out + (size_t)8388608;

  cvt5_kernel<<<12288, 256, 0, stream>>>(x, wq, wk, wv, wo, xb, wqb, wkb, wvb, wob);

  // fused QKV: M=4096, N=6144; 32x32 tiles of 128x192 -> 1024 blocks = 2 exact rounds
  gemmT<192, 0><<<dim3(1024), 512, 0, stream>>>(xb, wqb, qb, kb, vtb, nullptr, fc, fs);

  flash_kernel<<<dim3(32, 32), 256, 0, stream>>>(qb, kb, vtb, ab);

  // out-proj: M=4096, N=2048; 32x16 tiles of 128x128 -> 512 blocks = 1 exact round
  gemmT<128, 1><<<dim3(512), 512, 0, stream>>>(ab, wob, nullptr, nullptr, nullptr, out,
                                               nullptr, nullptr);
}

// Round 12
// 273.834 us; speedup vs baseline: 1.0893x; 1.0133x over previous
//
#include <hip/hip_runtime.h>

// Attention layer, MI355X. Internal bf16 MFMA compute (tolerance 7e-2 permits).
// R12: cvt5 -> tpose (cos/sin -> [ii][s], in dead d_out MB) -> fused QKV GEMM
// (BN=192, RoPE/V^T epilogue w/ f32x4 transposed-table loads, per-nf clustered,
// sched_barrier between bodies) -> flash (R5) -> out GEMM.
// gemmT core: BM=128 BK=32 ring-3, 1 barrier/tile, counted per-wave vmcnt,
// T2 swizzle, 2D XCD supertile (8x8 resident supertile per XCD).

#define SQ 2048
#define DQ 2048
#define HQ 16
#define HDQ 128

typedef short bf16x8 __attribute__((ext_vector_type(8)));
typedef short bf16x4 __attribute__((ext_vector_type(4)));
typedef float f32x4 __attribute__((ext_vector_type(4)));

#define WAITVM4 asm volatile("s_waitcnt vmcnt(4)" ::: "memory")
#define WAITVM3 asm volatile("s_waitcnt vmcnt(3)" ::: "memory")
#define WAITVM2 asm volatile("s_waitcnt vmcnt(2)" ::: "memory")
#define WAITVM0 asm volatile("s_waitcnt vmcnt(0)" ::: "memory")

__device__ __forceinline__ short f2bf(float f) {
  union { float f; unsigned u; } v; v.f = f;
  unsigned r = (v.u + 0x7FFFu + ((v.u >> 16) & 1u)) >> 16;
  return (short)r;
}
__device__ __forceinline__ float bf2f(short b) {
  union { unsigned u; float f; } v; v.u = ((unsigned)(unsigned short)b) << 16;
  return v.f;
}
__device__ __forceinline__ void gload_lds16(const void* g, void* l) {
  __builtin_amdgcn_global_load_lds(
      (const __attribute__((address_space(1))) void*)g,
      (__attribute__((address_space(3))) void*)l, 16, 0, 0);
}

// ---------- fp32 -> bf16, all 5 inputs in one launch ----------
__global__ void cvt5_kernel(const float* __restrict__ x, const float* __restrict__ wq,
                            const float* __restrict__ wk, const float* __restrict__ wv,
                            const float* __restrict__ wo, short* __restrict__ xb,
                            short* __restrict__ wqb, short* __restrict__ wkb,
                            short* __restrict__ wvb, short* __restrict__ wob) {
  int bi = blockIdx.x;
  const float* src;
  short* dst;
  int off;
  if (bi < 4096) {
    src = x; dst = xb; off = bi;
  } else {
    int t = bi - 4096, wsel = t >> 11;
    off = t & 2047;
    src = (wsel == 0) ? wq : (wsel == 1) ? wk : (wsel == 2) ? wv : wo;
    dst = (wsel == 0) ? wqb : (wsel == 1) ? wkb : (wsel == 2) ? wvb : wob;
  }
  int i = off * 256 + threadIdx.x;
  const f32x4* p = (const f32x4*)src + (size_t)i * 2;
  f32x4 a = p[0], b = p[1];
  bf16x8 o;
  o[0] = f2bf(a[0]); o[1] = f2bf(a[1]); o[2] = f2bf(a[2]); o[3] = f2bf(a[3]);
  o[4] = f2bf(b[0]); o[5] = f2bf(b[1]); o[6] = f2bf(b[2]); o[7] = f2bf(b[3]);
  *((bf16x8*)dst + i) = o;
}

// ---------- cos/sin tables [s][ii] -> transposed [ii][s] ----------
__global__ void tpose_kernel(const float* __restrict__ fc, const float* __restrict__ fs,
                             float* __restrict__ fct, float* __restrict__ fst) {
  __shared__ float tile[64][65];
  int s0 = blockIdx.x * 64, t = threadIdx.x;
#pragma unroll
  for (int it = 0; it < 16; ++it) {
    int idx = it * 256 + t;
    int r = idx >> 6, ii = idx & 63;
    tile[r][ii] = fc[(size_t)(s0 + r) * 64 + ii];
  }
  __syncthreads();
#pragma unroll
  for (int it = 0; it < 16; ++it) {
    int idx = it * 256 + t;
    int ii = idx >> 6, so = idx & 63;
    fct[(size_t)ii * 2048 + s0 + so] = tile[so][ii];
  }
  __syncthreads();
#pragma unroll
  for (int it = 0; it < 16; ++it) {
    int idx = it * 256 + t;
    int r = idx >> 6, ii = idx & 63;
    tile[r][ii] = fs[(size_t)(s0 + r) * 64 + ii];
  }
  __syncthreads();
#pragma unroll
  for (int it = 0; it < 16; ++it) {
    int idx = it * 256 + t;
    int ii = idx >> 6, so = idx & 63;
    fst[(size_t)ii * 2048 + s0 + so] = tile[so][ii];
  }
}

// ---------- gemmT: BM=128 x BN x BK=32, ring-3, 8 waves (2M x 4N), 1 barrier/tile ----------
// MODE 0 (BN=192): fused QKV + RoPE/V^T epilogue (transposed tables).
// MODE 1 (BN=128): fp32 [M][2048].
template <int BN, int MODE>
__global__ __launch_bounds__(512, 4) void gemmT(const short* __restrict__ A,
                                                const short* __restrict__ W,
                                                short* __restrict__ oQ, short* __restrict__ oK,
                                                short* __restrict__ oV, float* __restrict__ oF,
                                                const float* __restrict__ cosTt,
                                                const float* __restrict__ sinTt) {
  constexpr int NFR = BN / 64;   // B frags per wave
  constexpr int NIB = BN / 16;   // B stage issues (64 granules each)
  __shared__ __align__(16) short As[3][128 * 32];
  __shared__ __align__(16) short Bs[3][BN * 32];
  const int K = DQ;
  const int NT = K / 32;  // 64
  // 2D XCD supertiling: resident ~64 blocks per XCD form an 8x8 supertile.
  int x = blockIdx.x, xcd = x & 7, l = x >> 3;
  int by, bx;
  if (MODE == 0) {  // 32 by x 32 bx, XCD grid 2x4, chunk 16x8
    int xr = xcd >> 2, xc = xcd & 3;
    by = xr * 16 + (l >> 3);
    bx = xc * 8 + (l & 7);
  } else {          // 32 by x 16 bx, XCD grid 4x2, chunk 8x8
    int xr = xcd >> 1, xc = xcd & 1;
    by = xr * 8 + (l >> 3);
    bx = xc * 8 + (l & 7);
  }
  int m0 = by * 128, n0 = bx * BN;
  int tid = threadIdx.x, wid = tid >> 6, lane = tid & 63;
  int wr = wid >> 2, wc = wid & 3;
  f32x4 acc[4][NFR] = {};

  auto stageA = [&](int kt, int buf) {
    int g = wid * 64 + lane;
    int r = g >> 2, q = g & 3;
    gload_lds16(A + (size_t)(m0 + r) * K + kt * 32 + ((q ^ (((r >> 3) & 1) << 1)) * 8),
                &As[buf][wid * 512]);
  };
  auto stageB = [&](int kt, int buf) {
#pragma unroll
    for (int i = wid; i < NIB; i += 8) {
      int g = i * 64 + lane;
      int r = g >> 2, q = g & 3;
      gload_lds16(W + (size_t)(n0 + r) * K + kt * 32 + ((q ^ (((r >> 3) & 1) << 1)) * 8),
                  &Bs[buf][i * 512]);
    }
  };

  stageA(0, 0); stageB(0, 0);
  stageA(1, 1); stageB(1, 1);
  if (BN == 192 && wid < 4) { WAITVM3; } else { WAITVM2; }
  __builtin_amdgcn_s_barrier();

  int cc = (lane >> 4) * 8;
  int cur = 0, nbuf = 2;
#pragma unroll 1
  for (int t = 0; t < NT; ++t) {
    bool st = (t + 2) < NT;
    bf16x8 bfr[NFR], af[4];
#pragma unroll
    for (int nf = 0; nf < NFR; ++nf) {
      int br = wc * (BN / 4) + nf * 16 + (lane & 15);
      bfr[nf] = *(const bf16x8*)&Bs[cur][br * 32 + (cc ^ (((br >> 3) & 1) << 4))];
    }
#pragma unroll
    for (int i = 0; i < 4; ++i) {
      int fr = wr * 64 + i * 16 + (lane & 15);
      af[i] = *(const bf16x8*)&As[cur][fr * 32 + (cc ^ (((fr >> 3) & 1) << 4))];
    }
    if (st) { stageA(t + 2, nbuf); stageB(t + 2, nbuf); }
    __builtin_amdgcn_s_setprio(1);
#pragma unroll
    for (int i = 0; i < 4; ++i)
#pragma unroll
      for (int nf = 0; nf < NFR; ++nf)
        acc[i][nf] = __builtin_amdgcn_mfma_f32_16x16x32_bf16(af[i], bfr[nf], acc[i][nf], 0, 0, 0);
    __builtin_amdgcn_s_setprio(0);
    if (st) {
      if (BN == 192 && wid < 4) { WAITVM3; } else { WAITVM2; }
    } else {
      WAITVM0;
    }
    __builtin_amdgcn_s_barrier();
    cur = (cur == 2) ? 0 : cur + 1;
    nbuf = (nbuf == 2) ? 0 : nbuf + 1;
  }
  // ---- epilogue ----
  if (MODE == 1) {
#pragma unroll
    for (int mf = 0; mf < 4; ++mf) {
      int mb = m0 + wr * 64 + mf * 16 + (lane >> 4) * 4;
#pragma unroll
      for (int nf = 0; nf < NFR; ++nf) {
        int n_lin = n0 + wc * (BN / 4) + nf * 16 + (lane & 15);
#pragma unroll
        for (int j = 0; j < 4; ++j)
          oF[(size_t)(mb + j) * DQ + n_lin] = acc[mf][nf][j];
      }
    }
  } else {
#pragma unroll
    for (int nf = 0; nf < NFR; ++nf) {
      int n_lin = n0 + wc * (BN / 4) + nf * 16 + (lane & 15);
      int zsel = n_lin >> 11, col = n_lin & 2047;
      int h = col >> 7, hd = col & 127, ii = hd >> 1;
      if (zsel < 2) {
        float sgn = (hd & 1) ? 1.f : -1.f;
        float scl = (zsel == 0) ? 0.12751744779976827f : 1.f;  // log2e/sqrt(HD) for Q
        int sb = (m0 & 2047) + wr * 64 + (lane >> 4) * 4;
        f32x4 cv[4], sv[4];
#pragma unroll
        for (int mf = 0; mf < 4; ++mf) {
          cv[mf] = *(const f32x4*)&cosTt[(size_t)ii * 2048 + sb + mf * 16];
          sv[mf] = *(const f32x4*)&sinTt[(size_t)ii * 2048 + sb + mf * 16];
        }
        short* oT = zsel ? oK : oQ;
#pragma unroll
        for (int mf = 0; mf < 4; ++mf) {
          int mb = m0 + wr * 64 + mf * 16 + (lane >> 4) * 4;
#pragma unroll
          for (int j = 0; j < 4; ++j) {
            float v = acc[mf][nf][j];
            float vp = __shfl_xor(v, 1);  // RoPE pair (hd^1)
            float o = (v * cv[mf][j] + sgn * vp * sv[mf][j]) * scl;
            int m = mb + j;
            int s = m & 2047, bb = m >> 11;
            oT[(((size_t)(bb * HQ + h)) * SQ + s) * HDQ + hd] = f2bf(o);
          }
        }
      } else {
#pragma unroll
        for (int mf = 0; mf < 4; ++mf) {
          int mb = m0 + wr * 64 + mf * 16 + (lane >> 4) * 4;
          int bb = mb >> 11, s = mb & 2047;
          bf16x4 pk;
          pk[0] = f2bf(acc[mf][nf][0]); pk[1] = f2bf(acc[mf][nf][1]);
          pk[2] = f2bf(acc[mf][nf][2]); pk[3] = f2bf(acc[mf][nf][3]);
          *(bf16x4*)&oV[(((size_t)(bb * HQ + h)) * HDQ + hd) * SQ + s] = pk;
        }
      }
      __builtin_amdgcn_sched_barrier(0);  // keep each nf-body's loads local
    }
  }
}

// ---------- Flash attention R5: KVBLK=32 dbuf, swapped QK^T, 4 blocks/CU ----------
__device__ __forceinline__ void stage_kv32(const short* kbase, const short* vbase, int k0,
                                           short* KsB, short* VtB, int w, int lane) {
#pragma unroll
  for (int i = 0; i < 2; ++i) {
    int c = i * 4 + w;
    int ch = c * 64 + lane;
    int r = ch >> 4, c8 = (ch & 15) * 8;                   // K: [32 rows][128 d]
    gload_lds16(kbase + (size_t)(k0 + r) * HDQ + (c8 ^ ((r & 7) << 3)), KsB + c * 512);
    int d = ch >> 2, k8 = (ch & 3) * 8;                    // V^T: [128 d][32 k]
    gload_lds16(vbase + (size_t)d * SQ + k0 + (k8 ^ (((d >> 1) & 3) << 3)), VtB + c * 512);
  }
}

__global__ __launch_bounds__(256, 4) void flash_kernel(const short* __restrict__ qb,
                                                       const short* __restrict__ kb,
                                                       const short* __restrict__ vtb,
                                                       short* __restrict__ ab) {
  __shared__ __align__(16) short Ks[2][32 * 128];
  __shared__ __align__(16) short Vt[2][128 * 32];
  __shared__ __align__(16) short Pl[4][16 * 32];
  int x = blockIdx.x, bh = blockIdx.y;
  int qt = (bh & 8) ? (31 - x) : x;
  int q0 = qt * 64;
  int tid = threadIdx.x, w = tid >> 6, lane = tid & 63;
  int g = lane >> 4, qcol = lane & 15;
  int qw0 = q0 + w * 16;
  const short* qbase = qb + (size_t)bh * SQ * HDQ;
  const short* kbase = kb + (size_t)bh * SQ * HDQ;
  const short* vbase = vtb + (size_t)bh * HDQ * SQ;
  int b = bh >> 4, h = bh & 15;

  bf16x8 qf[4];
#pragma unroll
  for (int ccq = 0; ccq < 4; ++ccq)
    qf[ccq] = *(const bf16x8*)&qbase[(size_t)(qw0 + qcol) * HDQ + ccq * 32 + g * 8];

  f32x4 oacc[8] = {};
  float m_st = -1e30f, l_st = 0.f;
  int nt = 2 * qt + 2;
  stage_kv32(kbase, vbase, 0, Ks[0], Vt[0], w, lane);
#pragma unroll 1
  for (int t = 0; t < nt; ++t) {
    int cur = t & 1;
    int k0 = t * 32;
    __builtin_amdgcn_s_barrier();
    if (t + 1 < nt) {
      stage_kv32(kbase, vbase, (t + 1) * 32, Ks[cur ^ 1], Vt[cur ^ 1], w, lane);
      WAITVM4;
    } else {
      WAITVM0;
    }
    __builtin_amdgcn_s_barrier();
    if (k0 > qw0 + 15) continue;
    f32x4 sacc[2] = {};
    __builtin_amdgcn_s_setprio(1);
#pragma unroll
    for (int nf = 0; nf < 2; ++nf) {
      int rk = nf * 16 + qcol;
#pragma unroll
      for (int ccq = 0; ccq < 4; ++ccq) {
        int ck = ccq * 32 + g * 8;
        bf16x8 kf = *(const bf16x8*)&Ks[cur][rk * 128 + (ck ^ ((rk & 7) << 3))];
        sacc[nf] = __builtin_amdgcn_mfma_f32_16x16x32_bf16(kf, qf[ccq], sacc[nf], 0, 0, 0);
      }
    }
    __builtin_amdgcn_s_setprio(0);
    int q = qw0 + qcol;
    if (k0 + 31 > qw0) {
#pragma unroll
      for (int nf = 0; nf < 2; ++nf)
#pragma unroll
        for (int j = 0; j < 4; ++j) {
          int k = k0 + nf * 16 + g * 4 + j;
          if (k > q) sacc[nf][j] = -1e9f;
        }
    }
    float mt = fmaxf(fmaxf(fmaxf(sacc[0][0], sacc[0][1]), fmaxf(sacc[0][2], sacc[0][3])),
                     fmaxf(fmaxf(sacc[1][0], sacc[1][1]), fmaxf(sacc[1][2], sacc[1][3])));
    mt = fmaxf(mt, __shfl_xor(mt, 16));
    mt = fmaxf(mt, __shfl_xor(mt, 32));
    float mn = fmaxf(m_st, mt);
    float al = exp2f(m_st - mn);
    float p0[4], p1[4];
    float ls = 0.f;
#pragma unroll
    for (int j = 0; j < 4; ++j) { p0[j] = exp2f(sacc[0][j] - mn); ls += p0[j]; }
#pragma unroll
    for (int j = 0; j < 4; ++j) { p1[j] = exp2f(sacc[1][j] - mn); ls += p1[j]; }
    l_st = l_st * al + ls;
    m_st = mn;
    int sw = (qcol & 3) * 8;
    {
      bf16x4 pk;
      pk[0] = f2bf(p0[0]); pk[1] = f2bf(p0[1]); pk[2] = f2bf(p0[2]); pk[3] = f2bf(p0[3]);
      *(bf16x4*)&Pl[w][qcol * 32 + ((g * 4) ^ sw)] = pk;
      pk[0] = f2bf(p1[0]); pk[1] = f2bf(p1[1]); pk[2] = f2bf(p1[2]); pk[3] = f2bf(p1[3]);
      *(bf16x4*)&Pl[w][qcol * 32 + ((16 + g * 4) ^ sw)] = pk;
    }
    f32x4 alv;
    alv[0] = __shfl(al, g * 4 + 0);
    alv[1] = __shfl(al, g * 4 + 1);
    alv[2] = __shfl(al, g * 4 + 2);
    alv[3] = __shfl(al, g * 4 + 3);
#pragma unroll
    for (int df = 0; df < 8; ++df) oacc[df] *= alv;
    bf16x8 pf = *(const bf16x8*)&Pl[w][qcol * 32 + ((g * 8) ^ sw)];
    __builtin_amdgcn_s_setprio(1);
#pragma unroll
    for (int df = 0; df < 8; ++df) {
      int rd = df * 16 + qcol;
      bf16x8 vf = *(const bf16x8*)&Vt[cur][rd * 32 + ((g * 8) ^ (((rd >> 1) & 3) << 3))];
      oacc[df] = __builtin_amdgcn_mfma_f32_16x16x32_bf16(pf, vf, oacc[df], 0, 0, 0);
    }
    __builtin_amdgcn_s_setprio(0);
  }
  l_st += __shfl_xor(l_st, 16);
  l_st += __shfl_xor(l_st, 32);
  float inv = 1.0f / l_st;
  f32x4 invv;
  invv[0] = __shfl(inv, g * 4 + 0);
  invv[1] = __shfl(inv, g * 4 + 1);
  invv[2] = __shfl(inv, g * 4 + 2);
  invv[3] = __shfl(inv, g * 4 + 3);
#pragma unroll
  for (int df = 0; df < 8; ++df)
#pragma unroll
    for (int j = 0; j < 4; ++j) {
      int qq = qw0 + g * 4 + j;
      int dd = df * 16 + qcol;
      ab[((size_t)b * SQ + qq) * DQ + h * HDQ + dd] = f2bf(oacc[df][j] * invv[j]);
    }
}

extern "C" void kernel_launch(void* const* d_in, const int* in_sizes, int n_in,
                              void* d_out, int out_size, void* d_ws, size_t ws_size,
                              hipStream_t stream) {
  (void)in_sizes; (void)n_in; (void)out_size; (void)ws_size;
  const float* x  = (const float*)d_in[0];
  const float* wq = (const float*)d_in[1];
  const float* wk = (const float*)d_in[2];
  const float* wv = (const float*)d_in[3];
  const float* wo = (const float*)d_in[4];
  const float* fc = (const float*)d_in[5];
  const float* fs = (const float*)d_in[6];
  // d_in[7] = mask (implemented analytically: causal, start_pos=0), d_in[8] = start_pos
  float* out = (float*)d_out;

  short* xb  = (short*)d_ws;              // 8,388,608 elems
  short* wqb = xb + (size_t)8388608;      // wq,wk,wv contiguous: 6144 rows x 2048
  short* wkb = wqb + (size_t)4194304;
  short* wvb = wkb + (size_t)4194304;
  short* wob = wvb + (size_t)4194304;
  short* qb  = wob + (size_t)4194304;     // [B,H,S,HD] bf16 (RoPE'd + scaled)
  short* kb  = qb + (size_t)8388608;      // [B,H,S,HD] bf16 (RoPE'd)
  short* ab  = kb + (size_t)8388608;      // attn out [B,S,D] bf16
  // d_out overlays (dead until final GEMM): transposed tables in first 1MB,
  // V^T [BH,HD,S] in second half.
  float* fct = (float*)d_out;             // [64][2048] f32
  float* fst = fct + (size_t)131072;
  short* vtb = (short*)d_out + (size_t)8388608;

  cvt5_kernel<<<12288, 256, 0, stream>>>(x, wq, wk, wv, wo, xb, wqb, wkb, wvb, wob);
  tpose_kernel<<<32, 256, 0, stream>>>(fc, fs, fct, fst);

  // fused QKV: M=4096, N=6144; 32x32 tiles of 128x192 -> 1024 blocks = 2 exact rounds
  gemmT<192, 0><<<dim3(1024), 512, 0, stream>>>(xb, wqb, qb, kb, vtb, nullptr, fct, fst);

  flash_kernel<<<dim3(32, 32), 256, 0, stream>>>(qb, kb, vtb, ab);

  // out-proj: M=4096, N=2048; 32x16 tiles of 128x128 -> 512 blocks = 1 exact round
  gemmT<128, 1><<<dim3(512), 512, 0, stream>>>(ab, wob, nullptr, nullptr, nullptr, out,
                                               nullptr, nullptr);
}